// Round 1
// baseline (567.113 us; speedup 1.0000x reference)
//
#include <hip/hip_runtime.h>

// Haar tap magnitude: (1/sqrt(2))^3
#define SQ3F 0.35355339059327379f

// Forward 2x2x2 Haar butterfly. v index = z*4 + y*2 + x. o index = fz*4+fy*2+fx.
// dec_lo = [S,S], dec_hi = [-S,S]  -> hi = v1 - v0 (negative at pos 0)
__device__ __forceinline__ void haar_fwd(const float v[8], float o[8]) {
    float ax[8];
#pragma unroll
    for (int i = 0; i < 4; ++i) {
        float a = v[2 * i], b = v[2 * i + 1];
        ax[2 * i]     = a + b;   // fx = lo
        ax[2 * i + 1] = b - a;   // fx = hi
    }
    float ay[8];
#pragma unroll
    for (int z = 0; z < 2; ++z)
#pragma unroll
        for (int bx = 0; bx < 2; ++bx) {
            float a = ax[z * 4 + bx], b = ax[z * 4 + 2 + bx];
            ay[z * 4 + bx]     = a + b;  // fy = lo
            ay[z * 4 + 2 + bx] = b - a;  // fy = hi
        }
#pragma unroll
    for (int j = 0; j < 4; ++j) {
        float a = ay[j], b = ay[4 + j];
        o[j]     = (a + b) * SQ3F;  // fz = lo
        o[4 + j] = (b - a) * SQ3F;  // fz = hi
    }
}

// Inverse Haar. t index = fz*4+fy*2+fx. o index = z*4+y*2+x.
// rec_lo = [S,S], rec_hi = [S,-S] -> out[0] = lo+hi, out[1] = lo-hi
__device__ __forceinline__ void haar_inv(const float t[8], float o[8]) {
    float az[8];
#pragma unroll
    for (int j = 0; j < 4; ++j) {
        float lo = t[j], hi = t[4 + j];
        az[j]     = lo + hi;  // z = 0
        az[4 + j] = lo - hi;  // z = 1
    }
    float ay[8];
#pragma unroll
    for (int z = 0; z < 2; ++z)
#pragma unroll
        for (int bx = 0; bx < 2; ++bx) {
            float lo = az[z * 4 + bx], hi = az[z * 4 + 2 + bx];
            ay[z * 4 + bx]     = lo + hi;  // y = 0
            ay[z * 4 + 2 + bx] = lo - hi;  // y = 1
        }
#pragma unroll
    for (int i = 0; i < 4; ++i) {
        float lo = ay[2 * i], hi = ay[2 * i + 1];
        o[2 * i]     = (lo + hi) * SQ3F;  // x = 0
        o[2 * i + 1] = (lo - hi) * SQ3F;  // x = 1
    }
}

// DWT: one thread per (c, d, h, w) output site, SO = output spatial dim.
// Input channel c starts at in + c*inChStride, spatial dims SI=2*SO dense.
template <int SO>
__global__ __launch_bounds__(256) void dwt3_k(const float* __restrict__ in,
                                              int inChStride,
                                              float* __restrict__ out) {
    constexpr int SI = SO * 2;
    int idx = blockIdx.x * 256 + threadIdx.x;
    int w = idx % SO;
    int h = (idx / SO) % SO;
    int d = (idx / (SO * SO)) % SO;
    int c = idx / (SO * SO * SO);
    const float* ip = in + (long)c * inChStride;
    float v[8];
#pragma unroll
    for (int z = 0; z < 2; ++z)
#pragma unroll
        for (int y = 0; y < 2; ++y) {
            const float2 p =
                *(const float2*)(ip + ((2 * d + z) * SI + (2 * h + y)) * SI + 2 * w);
            v[z * 4 + y * 2]     = p.x;
            v[z * 4 + y * 2 + 1] = p.y;
        }
    float o[8];
    haar_fwd(v, o);
    int s = (d * SO + h) * SO + w;
#pragma unroll
    for (int f = 0; f < 8; ++f) out[(c * 8 + f) * (SO * SO * SO) + s] = o[f];
}

// Depthwise 3x3x3 SAME conv over 512 channels + soft-threshold (f!=0) + scale.
// blockIdx.y = channel cc (= c*8+f), blockIdx.x covers S^3 spatial.
template <int S>
__global__ __launch_bounds__(256) void dwconv_soft_k(const float* __restrict__ in,
                                                     const float* __restrict__ wt,
                                                     const float* __restrict__ wscale,
                                                     const float* __restrict__ lambd_p,
                                                     float* __restrict__ out) {
    int cc  = blockIdx.y;
    int idx = blockIdx.x * 256 + threadIdx.x;  // 0..S^3
    int w = idx % S, h = (idx / S) % S, d = idx / (S * S);
    const float* ip = in + (long)cc * (S * S * S);
    const float* wp = wt + cc * 27;
    float acc = 0.f;
#pragma unroll
    for (int dz = -1; dz <= 1; ++dz) {
        int zz = d + dz;
        if ((unsigned)zz >= (unsigned)S) continue;
#pragma unroll
        for (int dy = -1; dy <= 1; ++dy) {
            int yy = h + dy;
            if ((unsigned)yy >= (unsigned)S) continue;
#pragma unroll
            for (int dx = -1; dx <= 1; ++dx) {
                int xx = w + dx;
                if ((unsigned)xx >= (unsigned)S) continue;
                acc += ip[(zz * S + yy) * S + xx] * wp[(dz + 1) * 9 + (dy + 1) * 3 + (dx + 1)];
            }
        }
    }
    float t = acc;
    if (cc & 7) {  // soft-threshold high-frequency bands only
        float lam = *lambd_p;
        float a   = fabsf(t) - lam;
        t         = a > 0.f ? copysignf(a, t) : 0.f;
    }
    t *= wscale[cc];
    out[(long)cc * (S * S * S) + idx] = t;
}

// IDWT of t (64 ch x 8 bands x SI^3) accumulated (+=) into dst band-0 region
// (channel stride dstChStride, spatial dim 2*SI dense).
template <int SI>
__global__ __launch_bounds__(256) void idwt_add_k(const float* __restrict__ t,
                                                  float* __restrict__ dst,
                                                  int dstChStride) {
    int idx = blockIdx.x * 256 + threadIdx.x;
    int w = idx % SI, h = (idx / SI) % SI, d = (idx / (SI * SI)) % SI,
        c = idx / (SI * SI * SI);
    int s = (d * SI + h) * SI + w;
    float tf[8], o[8];
#pragma unroll
    for (int f = 0; f < 8; ++f) tf[f] = t[(c * 8 + f) * (SI * SI * SI) + s];
    haar_inv(tf, o);
    float* dp = dst + (long)c * dstChStride;
    constexpr int SD = SI * 2;
#pragma unroll
    for (int z = 0; z < 2; ++z)
#pragma unroll
        for (int y = 0; y < 2; ++y) {
            float* q = dp + ((2 * d + z) * SD + (2 * h + y)) * SD + 2 * w;
            q[0] += o[z * 4 + y * 2];
            q[1] += o[z * 4 + y * 2 + 1];
        }
}

// Final: out = (depthwise3x3x3(x, bw) + bb) * bscale + idwt3(t0).
// One thread per output voxel of (64, 64^3).
__global__ __launch_bounds__(256) void final_k(const float* __restrict__ x,
                                               const float* __restrict__ t0,
                                               const float* __restrict__ bw,
                                               const float* __restrict__ bb,
                                               const float* __restrict__ bscale,
                                               float* __restrict__ out) {
    int idx = blockIdx.x * 256 + threadIdx.x;
    int W = idx & 63, H = (idx >> 6) & 63, D = (idx >> 12) & 63, c = idx >> 18;
    const float* ip = x + (long)c * 262144;
    const float* wp = bw + c * 27;
    float acc = 0.f;
#pragma unroll
    for (int dz = -1; dz <= 1; ++dz) {
        int zz = D + dz;
        if ((unsigned)zz >= 64u) continue;
#pragma unroll
        for (int dy = -1; dy <= 1; ++dy) {
            int yy = H + dy;
            if ((unsigned)yy >= 64u) continue;
#pragma unroll
            for (int dx = -1; dx <= 1; ++dx) {
                int xx = W + dx;
                if ((unsigned)xx >= 64u) continue;
                acc += ip[(zz * 64 + yy) * 64 + xx] * wp[(dz + 1) * 9 + (dy + 1) * 3 + (dx + 1)];
            }
        }
    }
    float base = (acc + bb[c]) * bscale[c];

    int d = D >> 1, h = H >> 1, w = W >> 1;
    int z = D & 1, y = H & 1, xb = W & 1;
    int s = (d * 32 + h) * 32 + w;
    float o = 0.f;
#pragma unroll
    for (int f = 0; f < 8; ++f) {
        float v  = t0[(c * 8 + f) * 32768 + s];
        float sg = 1.f;
        if ((f & 4) && z) sg = -sg;   // rec_hi = [S, -S]: negative at pos 1
        if ((f & 2) && y) sg = -sg;
        if ((f & 1) && xb) sg = -sg;
        o += sg * v;
    }
    out[idx] = base + o * SQ3F;
}

extern "C" void kernel_launch(void* const* d_in, const int* in_sizes, int n_in,
                              void* d_out, int out_size, void* d_ws, size_t ws_size,
                              hipStream_t stream) {
    const float* x      = (const float*)d_in[0];  // (1,64,64,64,64)
    const float* base_w = (const float*)d_in[1];  // (64,1,3,3,3)
    const float* base_b = (const float*)d_in[2];  // (64,)
    const float* base_s = (const float*)d_in[3];  // (1,64,1,1,1)
    const float* w0     = (const float*)d_in[4];  // (512,1,3,3,3)
    const float* w1     = (const float*)d_in[5];  // (512,1,3,3,3)
    const float* ws0    = (const float*)d_in[6];  // (1,512,1,1,1)
    const float* ws1    = (const float*)d_in[7];  // (1,512,1,1,1)
    const float* lambd  = (const float*)d_in[8];  // scalar
    float* out = (float*)d_out;

    // Workspace layout (floats): cx0 16.7M | t0 16.7M | cx1 2.1M | t1 2.1M  = 144 MiB
    float* cx0 = (float*)d_ws;
    float* t0  = cx0 + 16777216;
    float* cx1 = t0 + 16777216;
    float* t1  = cx1 + 2097152;

    // Level 0: DWT of x -> cx0 (64ch x 8 bands x 32^3)
    dwt3_k<32><<<8192, 256, 0, stream>>>(x, 262144, cx0);
    // conv + soft-threshold + scale -> t0
    dwconv_soft_k<32><<<dim3(128, 512), 256, 0, stream>>>(cx0, w0, ws0, lambd, t0);
    // Level 1: DWT of raw LL band of cx0 -> cx1 (64ch x 8 x 16^3)
    dwt3_k<16><<<1024, 256, 0, stream>>>(cx0, 8 * 32768, cx1);
    dwconv_soft_k<16><<<dim3(16, 512), 256, 0, stream>>>(cx1, w1, ws1, lambd, t1);
    // Reconstruct level 1 and accumulate into t0 band 0
    idwt_add_k<16><<<1024, 256, 0, stream>>>(t1, t0, 8 * 32768);
    // Final: base depthwise conv + level-0 IDWT
    final_k<<<65536, 256, 0, stream>>>(x, t0, base_w, base_b, base_s, out);
}

// Round 2
// 253.952 us; speedup vs baseline: 2.2331x; 2.2331x over previous
//
#include <hip/hip_runtime.h>

// Haar tap magnitude: (1/sqrt(2))^3
#define SQ3F 0.35355339059327379f

// Forward 2x2x2 Haar butterfly. v index = z*4 + y*2 + x. o index = fz*4+fy*2+fx.
__device__ __forceinline__ void haar_fwd(const float v[8], float o[8]) {
    float ax[8];
#pragma unroll
    for (int i = 0; i < 4; ++i) {
        float a = v[2 * i], b = v[2 * i + 1];
        ax[2 * i]     = a + b;
        ax[2 * i + 1] = b - a;
    }
    float ay[8];
#pragma unroll
    for (int z = 0; z < 2; ++z)
#pragma unroll
        for (int bx = 0; bx < 2; ++bx) {
            float a = ax[z * 4 + bx], b = ax[z * 4 + 2 + bx];
            ay[z * 4 + bx]     = a + b;
            ay[z * 4 + 2 + bx] = b - a;
        }
#pragma unroll
    for (int j = 0; j < 4; ++j) {
        float a = ay[j], b = ay[4 + j];
        o[j]     = (a + b) * SQ3F;
        o[4 + j] = (b - a) * SQ3F;
    }
}

// Inverse Haar. t index = fz*4+fy*2+fx. o index = z*4+y*2+x.
__device__ __forceinline__ void haar_inv(const float t[8], float o[8]) {
    float az[8];
#pragma unroll
    for (int j = 0; j < 4; ++j) {
        float lo = t[j], hi = t[4 + j];
        az[j]     = lo + hi;
        az[4 + j] = lo - hi;
    }
    float ay[8];
#pragma unroll
    for (int z = 0; z < 2; ++z)
#pragma unroll
        for (int bx = 0; bx < 2; ++bx) {
            float lo = az[z * 4 + bx], hi = az[z * 4 + 2 + bx];
            ay[z * 4 + bx]     = lo + hi;
            ay[z * 4 + 2 + bx] = lo - hi;
        }
#pragma unroll
    for (int i = 0; i < 4; ++i) {
        float lo = ay[2 * i], hi = ay[2 * i + 1];
        o[2 * i]     = (lo + hi) * SQ3F;
        o[2 * i + 1] = (lo - hi) * SQ3F;
    }
}

// DWT: one thread per (c, d, h, w) output site, SO = output spatial dim.
template <int SO>
__global__ __launch_bounds__(256) void dwt3_k(const float* __restrict__ in,
                                              int inChStride,
                                              float* __restrict__ out) {
    constexpr int SI = SO * 2;
    int idx = blockIdx.x * 256 + threadIdx.x;
    int w = idx % SO;
    int h = (idx / SO) % SO;
    int d = (idx / (SO * SO)) % SO;
    int c = idx / (SO * SO * SO);
    const float* ip = in + (long)c * inChStride;
    float v[8];
#pragma unroll
    for (int z = 0; z < 2; ++z)
#pragma unroll
        for (int y = 0; y < 2; ++y) {
            const float2 p =
                *(const float2*)(ip + ((2 * d + z) * SI + (2 * h + y)) * SI + 2 * w);
            v[z * 4 + y * 2]     = p.x;
            v[z * 4 + y * 2 + 1] = p.y;
        }
    float o[8];
    haar_fwd(v, o);
    int s = (d * SO + h) * SO + w;
#pragma unroll
    for (int f = 0; f < 8; ++f) out[(c * 8 + f) * (SO * SO * SO) + s] = o[f];
}

// ---- Rolled depthwise conv + soft-threshold ------------------------------
// One step of the z-march. PH = zo % 3 (compile-time slot rotation).
// win[slot][dy][k] = input(plane, ty-1+dy, x0-1+k), plane->slot = plane % 3.
template <int S, int PH>
__device__ __forceinline__ void conv_step(const float* __restrict__ ip, int zo,
                                          int ty, int x0,
                                          const float* __restrict__ wv,
                                          float win[3][3][6], float lam, float sc,
                                          bool hf, float* __restrict__ op) {
    constexpr int sPrev = (PH + 2) % 3;
    constexpr int sCur  = PH;
    constexpr int sNext = (PH + 1) % 3;
    // Load plane zo+1 into slot sNext (zero-filled out of range).
    {
        int zz = zo + 1;
        bool zok = zz < S;
        const float* pp = ip + zz * S * S;
#pragma unroll
        for (int dy = 0; dy < 3; ++dy) {
            int yy  = ty - 1 + dy;
            bool yok = zok && ((unsigned)yy < (unsigned)S);
            const float* rp = pp + yy * S;
            win[sNext][dy][0] = (yok && x0 > 0) ? rp[x0 - 1] : 0.f;
            float4 m = yok ? *(const float4*)(rp + x0) : float4{0.f, 0.f, 0.f, 0.f};
            win[sNext][dy][1] = m.x;
            win[sNext][dy][2] = m.y;
            win[sNext][dy][3] = m.z;
            win[sNext][dy][4] = m.w;
            win[sNext][dy][5] = (yok && (x0 + 4 < S)) ? rp[x0 + 4] : 0.f;
        }
    }
    float acc[4] = {0.f, 0.f, 0.f, 0.f};
#pragma unroll
    for (int dz = 0; dz < 3; ++dz) {
        const float(*wp)[6] = (dz == 0) ? win[sPrev] : (dz == 1) ? win[sCur] : win[sNext];
#pragma unroll
        for (int dy = 0; dy < 3; ++dy)
#pragma unroll
            for (int dx = 0; dx < 3; ++dx) {
                float wgt = wv[dz * 9 + dy * 3 + dx];
#pragma unroll
                for (int j = 0; j < 4; ++j) acc[j] += wp[dy][dx + j] * wgt;
            }
    }
    float4 r;
    float* rr = (float*)&r;
#pragma unroll
    for (int j = 0; j < 4; ++j) {
        float t = acc[j];
        if (hf) {
            float a = fabsf(t) - lam;
            t       = a > 0.f ? copysignf(a, t) : 0.f;
        }
        rr[j] = t * sc;
    }
    *(float4*)(op + (zo * S + ty) * S + x0) = r;
}

// Block = CPB channels; thread = (tx: x-run of 4, ty: row). Marches z.
template <int S, int CPB>
__global__ __launch_bounds__(256) void dwconv_soft_roll_k(
    const float* __restrict__ in, const float* __restrict__ wt,
    const float* __restrict__ wscale, const float* __restrict__ lambd_p,
    float* __restrict__ out) {
    constexpr int TX = S / 4;
    int tid = threadIdx.x;
    int tx  = tid % TX;
    int ty  = (tid / TX) % S;
    int cs  = tid / (TX * S);
    int cc  = blockIdx.x * CPB + cs;
    const float* ip = in + (long)cc * (S * S * S);
    float* op       = out + (long)cc * (S * S * S);
    float wv[27];
#pragma unroll
    for (int k = 0; k < 27; ++k) wv[k] = wt[cc * 27 + k];
    float lam = *lambd_p;
    float sc  = wscale[cc];
    bool hf   = (cc & 7) != 0;
    int x0    = 4 * tx;

    float win[3][3][6];
#pragma unroll
    for (int a = 0; a < 3; ++a)
#pragma unroll
        for (int b = 0; b < 3; ++b)
#pragma unroll
            for (int k = 0; k < 6; ++k) win[a][b][k] = 0.f;
    // Preload plane 0 into slot 0 (slot 2 = plane -1 stays zero).
    {
#pragma unroll
        for (int dy = 0; dy < 3; ++dy) {
            int yy  = ty - 1 + dy;
            bool yok = (unsigned)yy < (unsigned)S;
            const float* rp = ip + yy * S;
            win[0][dy][0] = (yok && x0 > 0) ? rp[x0 - 1] : 0.f;
            float4 m = yok ? *(const float4*)(rp + x0) : float4{0.f, 0.f, 0.f, 0.f};
            win[0][dy][1] = m.x;
            win[0][dy][2] = m.y;
            win[0][dy][3] = m.z;
            win[0][dy][4] = m.w;
            win[0][dy][5] = (yok && (x0 + 4 < S)) ? rp[x0 + 4] : 0.f;
        }
    }
#pragma unroll 1
    for (int zb = 0; zb < S; zb += 3) {
        conv_step<S, 0>(ip, zb, ty, x0, wv, win, lam, sc, hf, op);
        if (zb + 1 < S) conv_step<S, 1>(ip, zb + 1, ty, x0, wv, win, lam, sc, hf, op);
        if (zb + 2 < S) conv_step<S, 2>(ip, zb + 2, ty, x0, wv, win, lam, sc, hf, op);
    }
}

// IDWT of t (64 ch x 8 bands x SI^3) accumulated (+=) into dst band-0 region.
template <int SI>
__global__ __launch_bounds__(256) void idwt_add_k(const float* __restrict__ t,
                                                  float* __restrict__ dst,
                                                  int dstChStride) {
    int idx = blockIdx.x * 256 + threadIdx.x;
    int w = idx % SI, h = (idx / SI) % SI, d = (idx / (SI * SI)) % SI,
        c = idx / (SI * SI * SI);
    int s = (d * SI + h) * SI + w;
    float tf[8], o[8];
#pragma unroll
    for (int f = 0; f < 8; ++f) tf[f] = t[(c * 8 + f) * (SI * SI * SI) + s];
    haar_inv(tf, o);
    float* dp = dst + (long)c * dstChStride;
    constexpr int SD = SI * 2;
#pragma unroll
    for (int z = 0; z < 2; ++z)
#pragma unroll
        for (int y = 0; y < 2; ++y) {
            float* q = dp + ((2 * d + z) * SD + (2 * h + y)) * SD + 2 * w;
            q[0] += o[z * 4 + y * 2];
            q[1] += o[z * 4 + y * 2 + 1];
        }
}

// Final: one thread per 2x2x2 output cube. base depthwise conv (4^3 patch,
// 8 reuse) + IDWT of t0 cell via haar_inv.
__global__ __launch_bounds__(256) void final_cube_k(const float* __restrict__ x,
                                                    const float* __restrict__ t0,
                                                    const float* __restrict__ bw,
                                                    const float* __restrict__ bb,
                                                    const float* __restrict__ bscale,
                                                    float* __restrict__ out) {
    int c    = blockIdx.x >> 7;  // 128 blocks per channel (32768 cells / 256)
    int cell = ((blockIdx.x & 127) << 8) + threadIdx.x;  // == (d*32+h)*32+w
    int w = cell & 31, h = (cell >> 5) & 31, d = cell >> 10;

    float tf[8];
#pragma unroll
    for (int f = 0; f < 8; ++f) tf[f] = t0[((c * 8 + f) << 15) + cell];
    float contrib[8];
    haar_inv(tf, contrib);

    const float* wp0 = bw + c * 27;  // c uniform per block -> scalar loads
    float wv[27];
#pragma unroll
    for (int k = 0; k < 27; ++k) wv[k] = wp0[k];
    float bias = bb[c], scl = bscale[c];

    const float* ip = x + ((long)c << 18);
    float p[4][4][4];
#pragma unroll
    for (int pz = 0; pz < 4; ++pz) {
        int zz  = 2 * d - 1 + pz;
        bool zok = (unsigned)zz < 64u;
#pragma unroll
        for (int py = 0; py < 4; ++py) {
            int yy  = 2 * h - 1 + py;
            bool yok = zok && ((unsigned)yy < 64u);
            const float* rp = ip + ((zz << 6) + yy) * 64;
#pragma unroll
            for (int px = 0; px < 4; ++px) {
                int xx = 2 * w - 1 + px;
                bool ok = yok && ((unsigned)xx < 64u);
                p[pz][py][px] = ok ? rp[xx] : 0.f;
            }
        }
    }
#pragma unroll
    for (int oz = 0; oz < 2; ++oz)
#pragma unroll
        for (int oy = 0; oy < 2; ++oy) {
            float r[2];
#pragma unroll
            for (int ox = 0; ox < 2; ++ox) {
                float acc = 0.f;
#pragma unroll
                for (int kz = 0; kz < 3; ++kz)
#pragma unroll
                    for (int ky = 0; ky < 3; ++ky)
#pragma unroll
                        for (int kx = 0; kx < 3; ++kx)
                            acc += p[oz + kz][oy + ky][ox + kx] * wv[kz * 9 + ky * 3 + kx];
                r[ox] = (acc + bias) * scl + contrib[oz * 4 + oy * 2 + ox];
            }
            *(float2*)(out + (((c << 6) + 2 * d + oz) * 64 + 2 * h + oy) * 64 + 2 * w) =
                float2{r[0], r[1]};
        }
}

extern "C" void kernel_launch(void* const* d_in, const int* in_sizes, int n_in,
                              void* d_out, int out_size, void* d_ws, size_t ws_size,
                              hipStream_t stream) {
    const float* x      = (const float*)d_in[0];
    const float* base_w = (const float*)d_in[1];
    const float* base_b = (const float*)d_in[2];
    const float* base_s = (const float*)d_in[3];
    const float* w0     = (const float*)d_in[4];
    const float* w1     = (const float*)d_in[5];
    const float* ws0    = (const float*)d_in[6];
    const float* ws1    = (const float*)d_in[7];
    const float* lambd  = (const float*)d_in[8];
    float* out = (float*)d_out;

    float* cx0 = (float*)d_ws;
    float* t0  = cx0 + 16777216;
    float* cx1 = t0 + 16777216;
    float* t1  = cx1 + 2097152;

    // Level 0
    dwt3_k<32><<<8192, 256, 0, stream>>>(x, 262144, cx0);
    dwconv_soft_roll_k<32, 1><<<512, 256, 0, stream>>>(cx0, w0, ws0, lambd, t0);
    // Level 1
    dwt3_k<16><<<1024, 256, 0, stream>>>(cx0, 8 * 32768, cx1);
    dwconv_soft_roll_k<16, 4><<<128, 256, 0, stream>>>(cx1, w1, ws1, lambd, t1);
    idwt_add_k<16><<<1024, 256, 0, stream>>>(t1, t0, 8 * 32768);
    // Final
    final_cube_k<<<8192, 256, 0, stream>>>(x, t0, base_w, base_b, base_s, out);
}